// Round 4
// baseline (125.591 us; speedup 1.0000x reference)
//
#include <hip/hip_runtime.h>
#include <math.h>
#include <limits.h>

#define EPS  1e-9f
#define TOPK 5

typedef float v4f __attribute__((ext_vector_type(4)));

// strict total order: higher val wins; on equal val, lower index wins
__device__ __forceinline__ bool better(float av, int ai, float bv, int bi) {
    return (av > bv) || (av == bv && ai < bi);
}

// insert (v,idx) into desc-sorted top-TOPK register arrays.
// Fully unrolled, all indices compile-time after unroll (no scratch).
__device__ __forceinline__ void insert_top(float sv[TOPK], int si[TOPK], float v, int idx) {
    if (!better(v, idx, sv[TOPK - 1], si[TOPK - 1])) return;
    sv[TOPK - 1] = v; si[TOPK - 1] = idx;
#pragma unroll
    for (int j = TOPK - 1; j > 0; --j) {
        if (better(sv[j], si[j], sv[j - 1], si[j - 1])) {
            float tv = sv[j]; sv[j] = sv[j - 1]; sv[j - 1] = tv;
            int   ti = si[j]; si[j] = si[j - 1]; si[j - 1] = ti;
        }
    }
}

__device__ __forceinline__ float dot4(v4f a, v4f b) {
    return a.x * b.x + a.y * b.y + a.z * b.z + a.w * b.w;
}

// ---------------------------------------------------------------------------
// Fused kernel: psi-norm (wave-redundant, from register fragments) +
// per-row cosine sim + per-block top-5 candidates.
// One wave per row-PAIR (8 independent float4 loads in flight, contiguous
// 8 KB stream); psi held in 16 VGPRs. After the butterfly, dot/nrm are
// WAVE-UNIFORM, so the sqrt/div and the top-5 insertion run on all 64 lanes
// identically -> zero divergence in the hot loop. Assumes D == 1024.
// ---------------------------------------------------------------------------
__global__ __launch_bounds__(256) void sim_top_kernel(const v4f* __restrict__ vocab,
                                                      const v4f* __restrict__ psi4,
                                                      float* __restrict__ cand_v,
                                                      int* __restrict__ cand_i,
                                                      int V) {
    __shared__ float wvs[4 * TOPK];
    __shared__ int   wis[4 * TOPK];
    const int tid  = threadIdx.x;
    const int lane = tid & 63;
    const int wave = tid >> 6;
    const int wavesPerBlock = blockDim.x >> 6;
    const int gwave  = blockIdx.x * wavesPerBlock + wave;
    const int nwaves = gridDim.x * wavesPerBlock;

    // psi fragments in registers: 64 lanes x 4 chunks = all 256 float4 of psi.
    const v4f p0 = psi4[lane];
    const v4f p1 = psi4[64 + lane];
    const v4f p2 = psi4[128 + lane];
    const v4f p3 = psi4[192 + lane];

    // wave-redundant ||psi||^2 -> scale (identical add order in every wave ->
    // bitwise-identical across the grid, deterministic)
    float ps = dot4(p0, p0) + dot4(p1, p1) + dot4(p2, p2) + dot4(p3, p3);
    for (int off = 32; off > 0; off >>= 1) ps += __shfl_xor(ps, off);
    const float scale = 1.0f / (sqrtf(ps) + EPS);

    float tv[TOPK]; int ti[TOPK];
#pragma unroll
    for (int j = 0; j < TOPK; ++j) { tv[j] = -INFINITY; ti[j] = INT_MAX; }

    const int NP = V >> 1;  // contiguous row pairs
    for (int p = gwave; p < NP; p += nwaves) {
        const v4f* ra = vocab + (size_t)(2 * p) * 256;
        const v4f* rb = ra + 256;
        v4f a0 = ra[lane];
        v4f a1 = ra[64 + lane];
        v4f a2 = ra[128 + lane];
        v4f a3 = ra[192 + lane];
        v4f b0 = rb[lane];
        v4f b1 = rb[64 + lane];
        v4f b2 = rb[128 + lane];
        v4f b3 = rb[192 + lane];

        float dotA = dot4(a0, p0) + dot4(a1, p1) + dot4(a2, p2) + dot4(a3, p3);
        float nrmA = dot4(a0, a0) + dot4(a1, a1) + dot4(a2, a2) + dot4(a3, a3);
        float dotB = dot4(b0, p0) + dot4(b1, p1) + dot4(b2, p2) + dot4(b3, p3);
        float nrmB = dot4(b0, b0) + dot4(b1, b1) + dot4(b2, b2) + dot4(b3, b3);

        // four independent butterfly chains, interleaved
        for (int off = 32; off > 0; off >>= 1) {
            dotA += __shfl_xor(dotA, off);
            nrmA += __shfl_xor(nrmA, off);
            dotB += __shfl_xor(dotB, off);
            nrmB += __shfl_xor(nrmB, off);
        }

        // wave-uniform epilogue: every lane computes & inserts identically
        float simA = dotA * scale / (sqrtf(nrmA) + EPS);
        float simB = dotB * scale / (sqrtf(nrmB) + EPS);
        insert_top(tv, ti, simA, 2 * p);
        insert_top(tv, ti, simB, 2 * p + 1);
    }

    // odd-V tail (not hit for V=128000)
    if ((V & 1) && gwave == 0) {
        const int row = V - 1;
        const v4f* ra = vocab + (size_t)row * 256;
        v4f a0 = ra[lane], a1 = ra[64 + lane], a2 = ra[128 + lane], a3 = ra[192 + lane];
        float dotA = dot4(a0, p0) + dot4(a1, p1) + dot4(a2, p2) + dot4(a3, p3);
        float nrmA = dot4(a0, a0) + dot4(a1, a1) + dot4(a2, a2) + dot4(a3, a3);
        for (int off = 32; off > 0; off >>= 1) {
            dotA += __shfl_xor(dotA, off);
            nrmA += __shfl_xor(nrmA, off);
        }
        insert_top(tv, ti, dotA * scale / (sqrtf(nrmA) + EPS), row);
    }

    if (lane == 0) {
#pragma unroll
        for (int j = 0; j < TOPK; ++j) { wvs[wave * TOPK + j] = tv[j]; wis[wave * TOPK + j] = ti[j]; }
    }
    __syncthreads();
    if (tid == 0) {
        float bv[TOPK]; int bi[TOPK];
#pragma unroll
        for (int j = 0; j < TOPK; ++j) { bv[j] = -INFINITY; bi[j] = INT_MAX; }
        for (int e = 0; e < wavesPerBlock * TOPK; ++e) insert_top(bv, bi, wvs[e], wis[e]);
#pragma unroll
        for (int j = 0; j < TOPK; ++j) {
            cand_v[blockIdx.x * TOPK + j] = bv[j];
            cand_i[blockIdx.x * TOPK + j] = bi[j];
        }
    }
}

// ---------------------------------------------------------------------------
// Reduce NC candidates -> global top-K. Single block; per-thread register
// top-5 -> wave butterfly merge -> LDS -> thread-0 final merge.
// out[0..K-1] = scores, out[K..2K-1] = indices (as float).
// ---------------------------------------------------------------------------
__global__ __launch_bounds__(1024) void topk_reduce_kernel(const float* __restrict__ cand_v,
                                                           const int* __restrict__ cand_i,
                                                           int NC, int K,
                                                           float* __restrict__ out) {
    __shared__ float wvs[16 * TOPK];
    __shared__ int   wis[16 * TOPK];
    const int tid = threadIdx.x;
    const int lane = tid & 63, wave = tid >> 6;
    const int nwaves = blockDim.x >> 6;

    float sv[TOPK]; int si[TOPK];
#pragma unroll
    for (int j = 0; j < TOPK; ++j) { sv[j] = -INFINITY; si[j] = INT_MAX; }

    for (int i = tid; i < NC; i += blockDim.x) insert_top(sv, si, cand_v[i], cand_i[i]);

    for (int step = 1; step < 64; step <<= 1) {
        float ov[TOPK]; int oi[TOPK];
#pragma unroll
        for (int j = 0; j < TOPK; ++j) {
            ov[j] = __shfl_xor(sv[j], step);
            oi[j] = __shfl_xor(si[j], step);
        }
#pragma unroll
        for (int j = 0; j < TOPK; ++j) insert_top(sv, si, ov[j], oi[j]);
    }

    if (lane == 0) {
#pragma unroll
        for (int j = 0; j < TOPK; ++j) { wvs[wave * TOPK + j] = sv[j]; wis[wave * TOPK + j] = si[j]; }
    }
    __syncthreads();
    if (tid == 0) {
        float bv[TOPK]; int bi[TOPK];
#pragma unroll
        for (int j = 0; j < TOPK; ++j) { bv[j] = -INFINITY; bi[j] = INT_MAX; }
        for (int e = 0; e < nwaves * TOPK; ++e) insert_top(bv, bi, wvs[e], wis[e]);
        for (int k = 0; k < K && k < TOPK; ++k) {
            out[k]     = bv[k];
            out[K + k] = (float)bi[k];
        }
    }
}

extern "C" void kernel_launch(void* const* d_in, const int* in_sizes, int n_in,
                              void* d_out, int out_size, void* d_ws, size_t ws_size,
                              hipStream_t stream) {
    const float* psi   = (const float*)d_in[0];
    const float* vocab = (const float*)d_in[1];
    const int D = in_sizes[0];           // 1024 (kernel assumes this)
    const int V = in_sizes[1] / D;       // 128000
    const int K = out_size / 2;          // 5
    (void)D;

    // 2000 blocks -> 8000 waves; 64000 row-pairs / 8000 = exactly 8 pairs/wave
    const int blocks = 2000;
    const int NC = blocks * TOPK;        // 10000 candidates

    float* cand_v = (float*)d_ws;
    int*   cand_i = (int*)((float*)d_ws + NC);

    sim_top_kernel<<<blocks, 256, 0, stream>>>((const v4f*)vocab, (const v4f*)psi,
                                               cand_v, cand_i, V);

    topk_reduce_kernel<<<1, 1024, 0, stream>>>(cand_v, cand_i, NC, K, (float*)d_out);
}

// Round 5
// 115.282 us; speedup vs baseline: 1.0894x; 1.0894x over previous
//
#include <hip/hip_runtime.h>
#include <math.h>
#include <limits.h>

#define EPS  1e-9f
#define TOPK 5

typedef float v4f __attribute__((ext_vector_type(4)));

// strict total order: higher val wins; on equal val, lower index wins
__device__ __forceinline__ bool better(float av, int ai, float bv, int bi) {
    return (av > bv) || (av == bv && ai < bi);
}

// insert (v,idx) into desc-sorted top-TOPK register arrays.
// Fully unrolled, all indices compile-time after unroll (no scratch).
__device__ __forceinline__ void insert_top(float sv[TOPK], int si[TOPK], float v, int idx) {
    if (!better(v, idx, sv[TOPK - 1], si[TOPK - 1])) return;
    sv[TOPK - 1] = v; si[TOPK - 1] = idx;
#pragma unroll
    for (int j = TOPK - 1; j > 0; --j) {
        if (better(sv[j], si[j], sv[j - 1], si[j - 1])) {
            float tv = sv[j]; sv[j] = sv[j - 1]; sv[j - 1] = tv;
            int   ti = si[j]; si[j] = si[j - 1]; si[j - 1] = ti;
        }
    }
}

__device__ __forceinline__ float dot4(v4f a, v4f b) {
    return a.x * b.x + a.y * b.y + a.z * b.z + a.w * b.w;
}

#define NTLOAD(p) __builtin_nontemporal_load(p)

// ---------------------------------------------------------------------------
// Fused kernel: psi-norm (wave-redundant, register fragments) + per-row
// cosine sim + per-block top-5 candidates.
// One wave per row-PAIR; nontemporal float4 loads (read-once 512MB stream);
// 2-deep software pipeline: next pair's 8 loads issue BEFORE the current
// pair's reduce/insert epilogue, overlapping HBM latency with the serial
// shfl chain. psi in 16 VGPRs. Assumes D == 1024 (256 float4/row).
// ---------------------------------------------------------------------------
__global__ __launch_bounds__(256) void sim_top_kernel(const v4f* __restrict__ vocab,
                                                      const v4f* __restrict__ psi4,
                                                      float* __restrict__ cand_v,
                                                      int* __restrict__ cand_i,
                                                      int V) {
    __shared__ float wvs[4 * TOPK];
    __shared__ int   wis[4 * TOPK];
    const int tid  = threadIdx.x;
    const int lane = tid & 63;
    const int wave = tid >> 6;
    const int wavesPerBlock = blockDim.x >> 6;
    const int gwave  = blockIdx.x * wavesPerBlock + wave;
    const int nwaves = gridDim.x * wavesPerBlock;

    // psi fragments in registers: 64 lanes x 4 chunks = all 256 float4 of psi.
    const v4f p0 = psi4[lane];
    const v4f p1 = psi4[64 + lane];
    const v4f p2 = psi4[128 + lane];
    const v4f p3 = psi4[192 + lane];

    // wave-redundant ||psi||^2 -> scale (identical add order in every wave)
    float ps = dot4(p0, p0) + dot4(p1, p1) + dot4(p2, p2) + dot4(p3, p3);
    for (int off = 32; off > 0; off >>= 1) ps += __shfl_xor(ps, off);
    const float scale = 1.0f / (sqrtf(ps) + EPS);

    float tv[TOPK]; int ti[TOPK];
#pragma unroll
    for (int j = 0; j < TOPK; ++j) { tv[j] = -INFINITY; ti[j] = INT_MAX; }

    const int NP = V >> 1;  // contiguous row pairs
    int p = gwave;
    if (p < NP) {
        // prologue: load pair p
        const v4f* ra = vocab + (size_t)(2 * p) * 256;
        v4f a0 = NTLOAD(ra + lane);
        v4f a1 = NTLOAD(ra + 64 + lane);
        v4f a2 = NTLOAD(ra + 128 + lane);
        v4f a3 = NTLOAD(ra + 192 + lane);
        v4f b0 = NTLOAD(ra + 256 + lane);
        v4f b1 = NTLOAD(ra + 320 + lane);
        v4f b2 = NTLOAD(ra + 384 + lane);
        v4f b3 = NTLOAD(ra + 448 + lane);

        while (true) {
            const int pn = p + nwaves;
            const bool more = pn < NP;    // wave-uniform
            v4f c0, c1, c2, c3, c4, c5, c6, c7;
            if (more) {
                const v4f* rn = vocab + (size_t)(2 * pn) * 256;
                c0 = NTLOAD(rn + lane);
                c1 = NTLOAD(rn + 64 + lane);
                c2 = NTLOAD(rn + 128 + lane);
                c3 = NTLOAD(rn + 192 + lane);
                c4 = NTLOAD(rn + 256 + lane);
                c5 = NTLOAD(rn + 320 + lane);
                c6 = NTLOAD(rn + 384 + lane);
                c7 = NTLOAD(rn + 448 + lane);
            }

            // compute current pair (waits only on the PREVIOUS batch)
            float dotA = dot4(a0, p0) + dot4(a1, p1) + dot4(a2, p2) + dot4(a3, p3);
            float nrmA = dot4(a0, a0) + dot4(a1, a1) + dot4(a2, a2) + dot4(a3, a3);
            float dotB = dot4(b0, p0) + dot4(b1, p1) + dot4(b2, p2) + dot4(b3, p3);
            float nrmB = dot4(b0, b0) + dot4(b1, b1) + dot4(b2, b2) + dot4(b3, b3);

            for (int off = 32; off > 0; off >>= 1) {
                dotA += __shfl_xor(dotA, off);
                nrmA += __shfl_xor(nrmA, off);
                dotB += __shfl_xor(dotB, off);
                nrmB += __shfl_xor(nrmB, off);
            }
            if (lane == 0) {
                insert_top(tv, ti, dotA * scale / (sqrtf(nrmA) + EPS), 2 * p);
                insert_top(tv, ti, dotB * scale / (sqrtf(nrmB) + EPS), 2 * p + 1);
            }

            if (!more) break;
            a0 = c0; a1 = c1; a2 = c2; a3 = c3;
            b0 = c4; b1 = c5; b2 = c6; b3 = c7;
            p = pn;
        }
    }

    // odd-V tail (not hit for V=128000)
    if ((V & 1) && gwave == 0) {
        const int row = V - 1;
        const v4f* ra = vocab + (size_t)row * 256;
        v4f a0 = ra[lane], a1 = ra[64 + lane], a2 = ra[128 + lane], a3 = ra[192 + lane];
        float dotA = dot4(a0, p0) + dot4(a1, p1) + dot4(a2, p2) + dot4(a3, p3);
        float nrmA = dot4(a0, a0) + dot4(a1, a1) + dot4(a2, a2) + dot4(a3, a3);
        for (int off = 32; off > 0; off >>= 1) {
            dotA += __shfl_xor(dotA, off);
            nrmA += __shfl_xor(nrmA, off);
        }
        if (lane == 0) insert_top(tv, ti, dotA * scale / (sqrtf(nrmA) + EPS), row);
    }

    if (lane == 0) {
#pragma unroll
        for (int j = 0; j < TOPK; ++j) { wvs[wave * TOPK + j] = tv[j]; wis[wave * TOPK + j] = ti[j]; }
    }
    __syncthreads();
    if (tid == 0) {
        float bv[TOPK]; int bi[TOPK];
#pragma unroll
        for (int j = 0; j < TOPK; ++j) { bv[j] = -INFINITY; bi[j] = INT_MAX; }
        for (int e = 0; e < wavesPerBlock * TOPK; ++e) insert_top(bv, bi, wvs[e], wis[e]);
#pragma unroll
        for (int j = 0; j < TOPK; ++j) {
            cand_v[blockIdx.x * TOPK + j] = bv[j];
            cand_i[blockIdx.x * TOPK + j] = bi[j];
        }
    }
}

// ---------------------------------------------------------------------------
// Reduce NC candidates -> global top-K. Single block; per-thread register
// top-5 -> wave butterfly merge -> LDS -> thread-0 final merge.
// out[0..K-1] = scores, out[K..2K-1] = indices (as float).
// ---------------------------------------------------------------------------
__global__ __launch_bounds__(1024) void topk_reduce_kernel(const float* __restrict__ cand_v,
                                                           const int* __restrict__ cand_i,
                                                           int NC, int K,
                                                           float* __restrict__ out) {
    __shared__ float wvs[16 * TOPK];
    __shared__ int   wis[16 * TOPK];
    const int tid = threadIdx.x;
    const int lane = tid & 63, wave = tid >> 6;
    const int nwaves = blockDim.x >> 6;

    float sv[TOPK]; int si[TOPK];
#pragma unroll
    for (int j = 0; j < TOPK; ++j) { sv[j] = -INFINITY; si[j] = INT_MAX; }

    for (int i = tid; i < NC; i += blockDim.x) insert_top(sv, si, cand_v[i], cand_i[i]);

    for (int step = 1; step < 64; step <<= 1) {
        float ov[TOPK]; int oi[TOPK];
#pragma unroll
        for (int j = 0; j < TOPK; ++j) {
            ov[j] = __shfl_xor(sv[j], step);
            oi[j] = __shfl_xor(si[j], step);
        }
#pragma unroll
        for (int j = 0; j < TOPK; ++j) insert_top(sv, si, ov[j], oi[j]);
    }

    if (lane == 0) {
#pragma unroll
        for (int j = 0; j < TOPK; ++j) { wvs[wave * TOPK + j] = sv[j]; wis[wave * TOPK + j] = si[j]; }
    }
    __syncthreads();
    if (tid == 0) {
        float bv[TOPK]; int bi[TOPK];
#pragma unroll
        for (int j = 0; j < TOPK; ++j) { bv[j] = -INFINITY; bi[j] = INT_MAX; }
        for (int e = 0; e < nwaves * TOPK; ++e) insert_top(bv, bi, wvs[e], wis[e]);
        for (int k = 0; k < K && k < TOPK; ++k) {
            out[k]     = bv[k];
            out[K + k] = (float)bi[k];
        }
    }
}

extern "C" void kernel_launch(void* const* d_in, const int* in_sizes, int n_in,
                              void* d_out, int out_size, void* d_ws, size_t ws_size,
                              hipStream_t stream) {
    const float* psi   = (const float*)d_in[0];
    const float* vocab = (const float*)d_in[1];
    const int D = in_sizes[0];           // 1024 (kernel assumes this)
    const int V = in_sizes[1] / D;       // 128000
    const int K = out_size / 2;          // 5
    (void)D;

    // 2000 blocks -> 8000 waves; 64000 row-pairs / 8000 = exactly 8 pairs/wave
    const int blocks = 2000;
    const int NC = blocks * TOPK;        // 10000 candidates

    float* cand_v = (float*)d_ws;
    int*   cand_i = (int*)((float*)d_ws + NC);

    sim_top_kernel<<<blocks, 256, 0, stream>>>((const v4f*)vocab, (const v4f*)psi,
                                               cand_v, cand_i, V);

    topk_reduce_kernel<<<1, 1024, 0, stream>>>(cand_v, cand_i, NC, K, (float*)d_out);
}